// Round 1
// baseline (212.049 us; speedup 1.0000x reference)
//
#include <hip/hip_runtime.h>
#include <hip/hip_bf16.h>
#include <stdint.h>

// Problem constants (from reference)
#define N_NODES_C 100000
#define N_EDGES_C 600000
#define H_C 128

// MFMA fragment types: 32x32x16 bf16 -> A/B = 8 bf16 (4 VGPR), C/D = 16 f32
typedef __bf16 bf16x8 __attribute__((ext_vector_type(8)));
typedef float f32x16 __attribute__((ext_vector_type(16)));

// fp32 -> bf16 round-to-nearest-even
__device__ __forceinline__ unsigned short f2bf(float f) {
    unsigned int u = __builtin_bit_cast(unsigned int, f);
    u += 0x7fffu + ((u >> 16) & 1u);
    return (unsigned short)(u >> 16);
}

// Kernel 1: z fp32 [N,128] -> bf16 rows (256 B each) in workspace
__global__ void zcast_kernel(const float* __restrict__ z,
                             unsigned short* __restrict__ zb, int n8) {
    int i = blockIdx.x * blockDim.x + threadIdx.x;  // 8 elements per thread
    if (i >= n8) return;
    const float4* p = reinterpret_cast<const float4*>(z) + (size_t)i * 2;
    float4 a = p[0], b = p[1];
    uint4 o;
    o.x = (unsigned)f2bf(a.x) | ((unsigned)f2bf(a.y) << 16);
    o.y = (unsigned)f2bf(a.z) | ((unsigned)f2bf(a.w) << 16);
    o.z = (unsigned)f2bf(b.x) | ((unsigned)f2bf(b.y) << 16);
    o.w = (unsigned)f2bf(b.z) | ((unsigned)f2bf(b.w) << 16);
    reinterpret_cast<uint4*>(zb)[i] = o;
}

// Kernel 2: W1 fp32 [256,128] -> bf16 in MFMA B-fragment order.
// Fragment (s = K-step 0..15, t = N-subtile 0..3): lane L holds
// B[k = s*16 + (L>>5)*8 + j][n = t*32 + (L&31)], j = 0..7 contiguous.
// Flat index: ((s*4 + t)*64 + L)*8 + j
__global__ void w1fmt_kernel(const float* __restrict__ W1,
                             unsigned short* __restrict__ w1f) {
    int i = blockIdx.x * blockDim.x + threadIdx.x;
    if (i >= 16 * 4 * 64 * 8) return;
    int j = i & 7;
    int L = (i >> 3) & 63;
    int t = (i >> 9) & 3;
    int s = i >> 11;
    int k = s * 16 + ((L >> 5) * 8) + j;      // 0..255 (src rows then dst rows of W1)
    int n = t * 32 + (L & 31);                // 0..127
    w1f[i] = f2bf(W1[k * H_C + n]);
}

// Main kernel: one wave handles 64 edges x all 128 fc1 outputs.
// A (gathered edge embeddings) loaded straight from global (lane reads the
// 16 B chunk matching the A-operand layout m=lane&31, k=(lane>>5)*8+j).
// B streamed coalesced from pre-formatted w1f. fc2 + bias + relu in fp32.
__launch_bounds__(256, 2)
__global__ void edge_mlp_kernel(const unsigned short* __restrict__ zb,
                                const int* __restrict__ ei,
                                const unsigned short* __restrict__ w1f,
                                const float* __restrict__ b1,
                                const float* __restrict__ w2,
                                const float* __restrict__ b2,
                                float* __restrict__ out) {
    const int lane = threadIdx.x & 63;
    const int wv   = threadIdx.x >> 6;
    const int tile = blockIdx.x * 4 + wv;          // 64-edge tile id
    if (tile >= N_EDGES_C / 64) return;
    const int e0   = tile * 64;
    const int l31  = lane & 31;
    const int half = lane >> 5;

    // Edge indices for this lane's two A-rows (Msub 0: edges e0..+31, Msub 1: +32..+63)
    const int em0 = e0 + l31;
    const int em1 = em0 + 32;
    const int si0 = ei[em0];
    const int si1 = ei[em1];
    const int di0 = ei[N_EDGES_C + em0];
    const int di1 = ei[N_EDGES_C + em1];

    const unsigned short* sr0 = zb + (size_t)si0 * H_C;
    const unsigned short* sr1 = zb + (size_t)si1 * H_C;
    const unsigned short* dr0 = zb + (size_t)di0 * H_C;
    const unsigned short* dr1 = zb + (size_t)di1 * H_C;

    f32x16 acc[2][4] = {};                          // 128 VGPRs of accumulator
    const int koff = half * 8;                      // element offset within K-chunk

    #pragma unroll
    for (int s = 0; s < 16; ++s) {
        // K-steps 0..7 read the src row (W1[:128]), 8..15 the dst row (W1[128:])
        const unsigned short* p0 = (s < 8 ? sr0 : dr0) + (s & 7) * 16 + koff;
        const unsigned short* p1 = (s < 8 ? sr1 : dr1) + (s & 7) * 16 + koff;
        bf16x8 a0 = *reinterpret_cast<const bf16x8*>(p0);
        bf16x8 a1 = *reinterpret_cast<const bf16x8*>(p1);
        const bf16x8* bp = reinterpret_cast<const bf16x8*>(w1f) + (s * 4) * 64 + lane;
        #pragma unroll
        for (int t = 0; t < 4; ++t) {
            bf16x8 b = bp[t * 64];
            acc[0][t] = __builtin_amdgcn_mfma_f32_32x32x16_bf16(a0, b, acc[0][t], 0, 0, 0);
            acc[1][t] = __builtin_amdgcn_mfma_f32_32x32x16_bf16(a1, b, acc[1][t], 0, 0, 0);
        }
    }

    // Epilogue: h = acc + b1 ; relu ; partial = sum_t relu(h)*w2 ; reduce over n-lanes
    float b1v[4], w2v[4];
    #pragma unroll
    for (int t = 0; t < 4; ++t) {
        int n = t * 32 + l31;                       // C/D col = lane&31
        b1v[t] = b1[n];
        w2v[t] = w2[n];
    }
    const float c2 = b2[0];

    #pragma unroll
    for (int i = 0; i < 2; ++i) {
        #pragma unroll
        for (int r = 0; r < 16; ++r) {
            float p = 0.0f;
            #pragma unroll
            for (int t = 0; t < 4; ++t) {
                float h = acc[i][t][r] + b1v[t];
                h = h > 0.0f ? h : 0.0f;
                p = fmaf(h, w2v[t], p);
            }
            // reduce across the 32 n-lanes within each half-wave
            p += __shfl_xor(p, 1);
            p += __shfl_xor(p, 2);
            p += __shfl_xor(p, 4);
            p += __shfl_xor(p, 8);
            p += __shfl_xor(p, 16);
            if (l31 == 0) {
                // C/D row = (r&3) + 8*(r>>2) + 4*(lane>>5)
                int row = (r & 3) + 8 * (r >> 2) + 4 * half;
                out[e0 + i * 32 + row] = p + c2;
            }
        }
    }
}

extern "C" void kernel_launch(void* const* d_in, const int* in_sizes, int n_in,
                              void* d_out, int out_size, void* d_ws, size_t ws_size,
                              hipStream_t stream) {
    const float* z  = (const float*)d_in[0];
    const int*   ei = (const int*)d_in[1];
    const float* W1 = (const float*)d_in[2];
    const float* b1 = (const float*)d_in[3];
    const float* W2 = (const float*)d_in[4];
    const float* b2 = (const float*)d_in[5];
    float* out = (float*)d_out;

    // Workspace layout: [z as bf16: 25.6 MB][W1 fragment-order bf16: 64 KB]
    unsigned short* zb  = (unsigned short*)d_ws;
    unsigned short* w1f = zb + (size_t)N_NODES_C * H_C;

    int n8 = N_NODES_C * H_C / 8;  // 1,600,000 vec8 groups
    zcast_kernel<<<(n8 + 255) / 256, 256, 0, stream>>>(z, zb, n8);
    w1fmt_kernel<<<(16 * 4 * 64 * 8 + 255) / 256, 256, 0, stream>>>(W1, w1f);

    int nwaves = N_EDGES_C / 64;   // 9375 tiles, 4 waves per block
    edge_mlp_kernel<<<(nwaves + 3) / 4, 256, 0, stream>>>(zb, ei, w1f, b1, W2, b2, out);
}

// Round 3
// 167.611 us; speedup vs baseline: 1.2651x; 1.2651x over previous
//
#include <hip/hip_runtime.h>
#include <hip/hip_bf16.h>
#include <stdint.h>

// Problem constants (from reference)
#define N_NODES_C 100000
#define N_EDGES_C 600000
#define H_C 128

// MFMA fragment types: 32x32x16 bf16 -> A/B = 8 bf16 (4 VGPR), C/D = 16 f32
typedef __bf16 bf16x8 __attribute__((ext_vector_type(8)));
typedef float f32x16 __attribute__((ext_vector_type(16)));
typedef _Float16 half8 __attribute__((ext_vector_type(8)));
typedef unsigned short ushort8 __attribute__((ext_vector_type(8)));

// fp32 -> bf16 round-to-nearest-even
__device__ __forceinline__ unsigned short f2bf(float f) {
    unsigned int u = __builtin_bit_cast(unsigned int, f);
    u += 0x7fffu + ((u >> 16) & 1u);
    return (unsigned short)(u >> 16);
}

// Kernel 1: W1 fp32 [256,128] -> bf16 combined-B in MFMA B-fragment order.
// Bc[k][n2], k=0..127, n2=0..255:  n2<128 -> W1[k][n2] (u path),
//                                  n2>=128 -> W1[128+k][n2-128] (v path).
// Fragment (s = K-step 0..7, t = N-subtile 0..7): lane L holds
// Bc[k = s*16 + (L>>5)*8 + j][n2 = t*32 + (L&31)], j = 0..7 contiguous.
// Flat index: ((s*8 + t)*64 + L)*8 + j   (32768 elements, 64 KB)
__global__ void w1fmt_kernel(const float* __restrict__ W1,
                             unsigned short* __restrict__ w1f) {
    int i = blockIdx.x * blockDim.x + threadIdx.x;
    if (i >= 8 * 8 * 64 * 8) return;
    int j = i & 7;
    int L = (i >> 3) & 63;
    int t = (i >> 9) & 7;
    int s = (i >> 12) & 7;
    int k  = s * 16 + ((L >> 5) * 8) + j;   // 0..127
    int n2 = t * 32 + (L & 31);             // 0..255
    float w = (n2 < 128) ? W1[k * H_C + n2]
                         : W1[(128 + k) * H_C + (n2 - 128)];
    w1f[i] = f2bf(w);
}

// Kernel 2: node GEMM. uv[0:N*128) = u' = z @ W1[:128] + b1 (fp16),
//           uv[N*128:) = v = z @ W1[128:] (fp16).
// One wave per 32 nodes; full N=256 (8 n-subtiles of 32), K=128 (8 steps).
// A read directly from fp32 z (each lane: 32 B of its row per K-step).
__launch_bounds__(256, 2)
__global__ void node_gemm_kernel(const float* __restrict__ z,
                                 const unsigned short* __restrict__ w1f,
                                 const float* __restrict__ b1,
                                 _Float16* __restrict__ uv) {
    const int lane = threadIdx.x & 63;
    const int wv   = threadIdx.x >> 6;
    const int tile = blockIdx.x * 4 + wv;       // 32-node tile
    if (tile >= N_NODES_C / 32) return;
    const int l31  = lane & 31;
    const int half = lane >> 5;

    const float* arow = z + (size_t)(tile * 32 + l31) * H_C + half * 8;
    f32x16 acc[8] = {};

    #pragma unroll
    for (int s = 0; s < 8; ++s) {
        float4 alo = *reinterpret_cast<const float4*>(arow + s * 16);
        float4 ahi = *reinterpret_cast<const float4*>(arow + s * 16 + 4);
        ushort8 au;
        au[0] = f2bf(alo.x); au[1] = f2bf(alo.y);
        au[2] = f2bf(alo.z); au[3] = f2bf(alo.w);
        au[4] = f2bf(ahi.x); au[5] = f2bf(ahi.y);
        au[6] = f2bf(ahi.z); au[7] = f2bf(ahi.w);
        bf16x8 a = __builtin_bit_cast(bf16x8, au);
        const bf16x8* bp = reinterpret_cast<const bf16x8*>(w1f) + (s * 8) * 64 + lane;
        #pragma unroll
        for (int t = 0; t < 8; ++t) {
            bf16x8 b = bp[t * 64];
            acc[t] = __builtin_amdgcn_mfma_f32_32x32x16_bf16(a, b, acc[t], 0, 0, 0);
        }
    }

    // Epilogue: +b1 on the u half, convert to fp16, pack adjacent columns
    // (adjacent lanes) via shuffle, even lanes store dwords.
    const int node0 = tile * 32;
    #pragma unroll
    for (int t = 0; t < 8; ++t) {
        float badd = (t < 4) ? b1[t * 32 + l31] : 0.0f;
        size_t colbase = (t < 4) ? (size_t)(t * 32 + l31)
                                 : ((size_t)N_NODES_C * H_C + (size_t)((t - 4) * 32 + l31));
        #pragma unroll
        for (int r = 0; r < 16; ++r) {
            int row = (r & 3) + 8 * (r >> 2) + 4 * half;    // C/D row mapping
            float v = acc[t][r] + badd;
            float fother = __shfl_xor(v, 1);
            if ((lane & 1) == 0) {
                unsigned int pk = __builtin_bit_cast(
                    unsigned int, __builtin_amdgcn_cvt_pkrtz(v, fother));
                size_t idx = (size_t)(node0 + row) * H_C + colbase;  // even
                *reinterpret_cast<unsigned int*>(uv + idx) = pk;
            }
        }
    }
}

// Kernel 3: edge phase. Quarter-wave (16 lanes) per edge: each lane loads
// 16 B (8 fp16) of u'[src] and v[dst]; h = u+v; relu; dot with its W2 slice;
// 4-step xor-shuffle reduce; lane 0 writes. 2 edges per quarter per iter
// for memory-level parallelism.
__global__ void edge_kernel(const _Float16* __restrict__ uv,
                            const int* __restrict__ ei,
                            const float* __restrict__ w2,
                            const float* __restrict__ b2,
                            float* __restrict__ out) {
    const int tid = blockIdx.x * blockDim.x + threadIdx.x;
    const int j   = tid & 15;                       // lane within quarter
    const int q   = tid >> 4;                       // global quarter id
    const int nq  = (gridDim.x * blockDim.x) >> 4;  // total quarters

    float w2v[8];
    {
        float4 a = *reinterpret_cast<const float4*>(w2 + j * 8);
        float4 b = *reinterpret_cast<const float4*>(w2 + j * 8 + 4);
        w2v[0] = a.x; w2v[1] = a.y; w2v[2] = a.z; w2v[3] = a.w;
        w2v[4] = b.x; w2v[5] = b.y; w2v[6] = b.z; w2v[7] = b.w;
    }
    const float c2 = b2[0];
    const _Float16* vbase = uv + (size_t)N_NODES_C * H_C;

    for (int e = q; e < N_EDGES_C; e += 2 * nq) {
        const int e1 = e + nq;
        const bool has1 = (e1 < N_EDGES_C);
        int s0 = ei[e];
        int d0 = ei[N_EDGES_C + e];
        int s1 = has1 ? ei[e1] : s0;
        int d1 = has1 ? ei[N_EDGES_C + e1] : d0;

        half8 u0 = *reinterpret_cast<const half8*>(uv    + (size_t)s0 * H_C + j * 8);
        half8 v0 = *reinterpret_cast<const half8*>(vbase + (size_t)d0 * H_C + j * 8);
        half8 u1 = *reinterpret_cast<const half8*>(uv    + (size_t)s1 * H_C + j * 8);
        half8 v1 = *reinterpret_cast<const half8*>(vbase + (size_t)d1 * H_C + j * 8);

        float p0 = 0.0f, p1 = 0.0f;
        #pragma unroll
        for (int k = 0; k < 8; ++k) {
            float h0 = (float)u0[k] + (float)v0[k];
            float h1 = (float)u1[k] + (float)v1[k];
            h0 = h0 > 0.0f ? h0 : 0.0f;
            h1 = h1 > 0.0f ? h1 : 0.0f;
            p0 = fmaf(h0, w2v[k], p0);
            p1 = fmaf(h1, w2v[k], p1);
        }
        p0 += __shfl_xor(p0, 1);  p1 += __shfl_xor(p1, 1);
        p0 += __shfl_xor(p0, 2);  p1 += __shfl_xor(p1, 2);
        p0 += __shfl_xor(p0, 4);  p1 += __shfl_xor(p1, 4);
        p0 += __shfl_xor(p0, 8);  p1 += __shfl_xor(p1, 8);
        if (j == 0) {
            out[e] = p0 + c2;
            if (has1) out[e1] = p1 + c2;
        }
    }
}

extern "C" void kernel_launch(void* const* d_in, const int* in_sizes, int n_in,
                              void* d_out, int out_size, void* d_ws, size_t ws_size,
                              hipStream_t stream) {
    const float* z  = (const float*)d_in[0];
    const int*   ei = (const int*)d_in[1];
    const float* W1 = (const float*)d_in[2];
    const float* b1 = (const float*)d_in[3];
    const float* W2 = (const float*)d_in[4];
    const float* b2 = (const float*)d_in[5];
    float* out = (float*)d_out;

    // Workspace: [w1f: 64 KB][uv: u' then v, 2 * 100000*128 fp16 = 51.2 MB]
    unsigned short* w1f = (unsigned short*)d_ws;
    _Float16* uv = (_Float16*)((char*)d_ws + 65536);

    w1fmt_kernel<<<(8 * 8 * 64 * 8 + 255) / 256, 256, 0, stream>>>(W1, w1f);

    int ntiles = N_NODES_C / 32;   // 3125
    node_gemm_kernel<<<(ntiles + 3) / 4, 256, 0, stream>>>(z, w1f, b1, uv);

    edge_kernel<<<2048, 256, 0, stream>>>(uv, ei, W2, b2, out);
}

// Round 4
// 162.393 us; speedup vs baseline: 1.3058x; 1.0321x over previous
//
#include <hip/hip_runtime.h>
#include <hip/hip_bf16.h>
#include <stdint.h>

// Problem constants (from reference)
#define N_NODES_C 100000
#define N_EDGES_C 600000
#define H_C 128

// MFMA fragment types: 32x32x16 bf16 -> A/B = 8 bf16 (4 VGPR), C/D = 16 f32
typedef __bf16 bf16x8 __attribute__((ext_vector_type(8)));
typedef float f32x16 __attribute__((ext_vector_type(16)));
typedef _Float16 half8 __attribute__((ext_vector_type(8)));
typedef unsigned short ushort8 __attribute__((ext_vector_type(8)));

// fp32 -> bf16 round-to-nearest-even
__device__ __forceinline__ unsigned short f2bf(float f) {
    unsigned int u = __builtin_bit_cast(unsigned int, f);
    u += 0x7fffu + ((u >> 16) & 1u);
    return (unsigned short)(u >> 16);
}

// Kernel 1: W1 fp32 [256,128] -> bf16 combined-B in MFMA B-fragment order.
// Bc[k][n2], k=0..127, n2=0..255:  n2<128 -> W1[k][n2] (u path),
//                                  n2>=128 -> W1[128+k][n2-128] (v path).
// Fragment (s = K-step 0..7, t = N-subtile 0..7): lane L holds
// Bc[k = s*16 + (L>>5)*8 + j][n2 = t*32 + (L&31)], j = 0..7 contiguous.
// Flat index: ((s*8 + t)*64 + L)*8 + j   (32768 elements, 64 KB)
__global__ void w1fmt_kernel(const float* __restrict__ W1,
                             unsigned short* __restrict__ w1f) {
    int i = blockIdx.x * blockDim.x + threadIdx.x;
    if (i >= 8 * 8 * 64 * 8) return;
    int j = i & 7;
    int L = (i >> 3) & 63;
    int t = (i >> 9) & 7;
    int s = (i >> 12) & 7;
    int k  = s * 16 + ((L >> 5) * 8) + j;   // 0..127
    int n2 = t * 32 + (L & 31);             // 0..255
    float w = (n2 < 128) ? W1[k * H_C + n2]
                         : W1[(128 + k) * H_C + (n2 - 128)];
    w1f[i] = f2bf(w);
}

// Kernel 2: node GEMM. uv[0:N*128) = u' = z @ W1[:128] + b1 (fp16),
//           uv[N*128:) = v = z @ W1[128:] (fp16).
// One wave per (32-node tile, u/v half): N=128 per wave (4 n-subtiles),
// K=128 (8 steps). acc = 64 AGPRs -> 3 waves/SIMD. 6250 waves total.
__launch_bounds__(256, 3)
__global__ void node_gemm_kernel(const float* __restrict__ z,
                                 const unsigned short* __restrict__ w1f,
                                 const float* __restrict__ b1,
                                 _Float16* __restrict__ uv) {
    const int lane = threadIdx.x & 63;
    const int wv   = threadIdx.x >> 6;
    const int wid  = blockIdx.x * 4 + wv;       // global wave id
    if (wid >= 2 * (N_NODES_C / 32)) return;    // 6250
    const int tile = wid >> 1;                  // 32-node tile
    const int uh   = wid & 1;                   // 0 = u (with b1), 1 = v
    const int l31  = lane & 31;
    const int half = lane >> 5;

    const float* arow = z + (size_t)(tile * 32 + l31) * H_C + half * 8;
    f32x16 acc[4] = {};

    #pragma unroll
    for (int s = 0; s < 8; ++s) {
        float4 alo = *reinterpret_cast<const float4*>(arow + s * 16);
        float4 ahi = *reinterpret_cast<const float4*>(arow + s * 16 + 4);
        ushort8 au;
        au[0] = f2bf(alo.x); au[1] = f2bf(alo.y);
        au[2] = f2bf(alo.z); au[3] = f2bf(alo.w);
        au[4] = f2bf(ahi.x); au[5] = f2bf(ahi.y);
        au[6] = f2bf(ahi.z); au[7] = f2bf(ahi.w);
        bf16x8 a = __builtin_bit_cast(bf16x8, au);
        const bf16x8* bp = reinterpret_cast<const bf16x8*>(w1f)
                           + (s * 8 + uh * 4) * 64 + lane;
        #pragma unroll
        for (int t = 0; t < 4; ++t) {
            bf16x8 b = bp[t * 64];
            acc[t] = __builtin_amdgcn_mfma_f32_32x32x16_bf16(a, b, acc[t], 0, 0, 0);
        }
    }

    // Epilogue: +b1 on the u half, convert to fp16, pack adjacent columns
    // (adjacent lanes) via shuffle, even lanes store dwords.
    const int node0 = tile * 32;
    const size_t segbase = uh ? (size_t)N_NODES_C * H_C : 0;
    #pragma unroll
    for (int t = 0; t < 4; ++t) {
        int n = t * 32 + l31;                   // column 0..127
        float badd = uh ? 0.0f : b1[n];
        #pragma unroll
        for (int r = 0; r < 16; ++r) {
            int row = (r & 3) + 8 * (r >> 2) + 4 * half;    // C/D row mapping
            float v = acc[t][r] + badd;
            float fother = __shfl_xor(v, 1);
            if ((lane & 1) == 0) {
                unsigned int pk = __builtin_bit_cast(
                    unsigned int, __builtin_amdgcn_cvt_pkrtz(v, fother));
                size_t idx = segbase + (size_t)(node0 + row) * H_C + n;  // n even
                *reinterpret_cast<unsigned int*>(uv + idx) = pk;
            }
        }
    }
}

// Kernel 3: edge phase. Quarter-wave (16 lanes) per FOUR consecutive edges:
// indices via two broadcast int4 loads; 8 row-gathers (16 B/lane) in flight;
// per-edge dot with W2 slice; 4-step xor-shuffle reduce; lane 0 stores float4.
__global__ void edge_kernel(const _Float16* __restrict__ uv,
                            const int* __restrict__ ei,
                            const float* __restrict__ w2,
                            const float* __restrict__ b2,
                            float* __restrict__ out) {
    const int tid = blockIdx.x * blockDim.x + threadIdx.x;
    const int j   = tid & 15;                       // lane within quarter
    const int q   = tid >> 4;                       // quarter id
    const int e0  = q * 4;
    if (e0 >= N_EDGES_C) return;

    float w2v[8];
    {
        float4 a = *reinterpret_cast<const float4*>(w2 + j * 8);
        float4 b = *reinterpret_cast<const float4*>(w2 + j * 8 + 4);
        w2v[0] = a.x; w2v[1] = a.y; w2v[2] = a.z; w2v[3] = a.w;
        w2v[4] = b.x; w2v[5] = b.y; w2v[6] = b.z; w2v[7] = b.w;
    }
    const float c2 = b2[0];
    const _Float16* vbase = uv + (size_t)N_NODES_C * H_C;

    int4 ss = *reinterpret_cast<const int4*>(ei + e0);
    int4 dd = *reinterpret_cast<const int4*>(ei + N_EDGES_C + e0);

    half8 u0 = *reinterpret_cast<const half8*>(uv    + (size_t)ss.x * H_C + j * 8);
    half8 v0 = *reinterpret_cast<const half8*>(vbase + (size_t)dd.x * H_C + j * 8);
    half8 u1 = *reinterpret_cast<const half8*>(uv    + (size_t)ss.y * H_C + j * 8);
    half8 v1 = *reinterpret_cast<const half8*>(vbase + (size_t)dd.y * H_C + j * 8);
    half8 u2 = *reinterpret_cast<const half8*>(uv    + (size_t)ss.z * H_C + j * 8);
    half8 v2 = *reinterpret_cast<const half8*>(vbase + (size_t)dd.z * H_C + j * 8);
    half8 u3 = *reinterpret_cast<const half8*>(uv    + (size_t)ss.w * H_C + j * 8);
    half8 v3 = *reinterpret_cast<const half8*>(vbase + (size_t)dd.w * H_C + j * 8);

    float p0 = 0.0f, p1 = 0.0f, p2 = 0.0f, p3 = 0.0f;
    #pragma unroll
    for (int k = 0; k < 8; ++k) {
        float h0 = (float)u0[k] + (float)v0[k];
        float h1 = (float)u1[k] + (float)v1[k];
        float h2 = (float)u2[k] + (float)v2[k];
        float h3 = (float)u3[k] + (float)v3[k];
        h0 = h0 > 0.0f ? h0 : 0.0f;
        h1 = h1 > 0.0f ? h1 : 0.0f;
        h2 = h2 > 0.0f ? h2 : 0.0f;
        h3 = h3 > 0.0f ? h3 : 0.0f;
        p0 = fmaf(h0, w2v[k], p0);
        p1 = fmaf(h1, w2v[k], p1);
        p2 = fmaf(h2, w2v[k], p2);
        p3 = fmaf(h3, w2v[k], p3);
    }
    #pragma unroll
    for (int m = 1; m <= 8; m <<= 1) {
        p0 += __shfl_xor(p0, m);
        p1 += __shfl_xor(p1, m);
        p2 += __shfl_xor(p2, m);
        p3 += __shfl_xor(p3, m);
    }
    if (j == 0) {
        float4 o = { p0 + c2, p1 + c2, p2 + c2, p3 + c2 };
        *reinterpret_cast<float4*>(out + e0) = o;
    }
}

extern "C" void kernel_launch(void* const* d_in, const int* in_sizes, int n_in,
                              void* d_out, int out_size, void* d_ws, size_t ws_size,
                              hipStream_t stream) {
    const float* z  = (const float*)d_in[0];
    const int*   ei = (const int*)d_in[1];
    const float* W1 = (const float*)d_in[2];
    const float* b1 = (const float*)d_in[3];
    const float* W2 = (const float*)d_in[4];
    const float* b2 = (const float*)d_in[5];
    float* out = (float*)d_out;

    // Workspace: [w1f: 64 KB][uv: u' then v, 2 * 100000*128 fp16 = 51.2 MB]
    unsigned short* w1f = (unsigned short*)d_ws;
    _Float16* uv = (_Float16*)((char*)d_ws + 65536);

    w1fmt_kernel<<<(8 * 8 * 64 * 8 + 255) / 256, 256, 0, stream>>>(W1, w1f);

    int nwaves = 2 * (N_NODES_C / 32);   // 6250
    node_gemm_kernel<<<(nwaves + 3) / 4, 256, 0, stream>>>(z, w1f, b1, uv);

    int nquarters = N_EDGES_C / 4;       // 150000
    edge_kernel<<<(nquarters * 16 + 255) / 256, 256, 0, stream>>>(uv, ei, W2, b2, out);
}